// Round 10
// baseline (18.342 us; speedup 1.0000x reference)
//
#include <hip/hip_runtime.h>
#include <hip/hip_cooperative_groups.h>

namespace cg = cooperative_groups;

// Problem constants (fixed by reference setup_inputs)
constexpr int B_ = 32;
constexpr int S_ = 4096;
constexpr int D_ = 256;
constexpr int PAIRS_PER_BATCH = S_ - 1;                                   // 4095
constexpr int CHUNK = 16;                                                 // pairs per chunk
constexpr int CHUNKS_PER_BATCH = (PAIRS_PER_BATCH + CHUNK - 1) / CHUNK;   // 256
constexpr int NCHUNKS = B_ * CHUNKS_PER_BATCH;                            // 8192
constexpr int BLOCK = 256;
constexpr int WAVES_PER_BLOCK = BLOCK / 64;                               // 4
constexpr int NBLOCKS = 512;                                              // 2 blocks/CU needed
constexpr int NWAVES = NBLOCKS * WAVES_PER_BLOCK;                         // 2048 -> 4 chunks/wave

// Process TWO chunks with their memory phases overlapped: both label loads
// issued together, both masks via ballot, both row-load sets issued, then
// (sched_barrier) compute both. Halves the exposed L3 latency vs serial
// chunk-at-a-time. All branches wave-uniform.
__device__ __forceinline__ float pair_sum(const float* __restrict__ emb,
                                          const int* __restrict__ lab,
                                          int cA, int cB, int lane) {
  const int bA = cA / CHUNKS_PER_BATCH, ccA = cA % CHUNKS_PER_BATCH;
  const int bB = cB / CHUNKS_PER_BATCH, ccB = cB % CHUNKS_PER_BATCH;
  const int pA = ccA * CHUNK, pB = ccB * CHUNK;
  const int nA = min(CHUNK, PAIRS_PER_BATCH - pA);   // 16 (15 for last chunk)
  const int nB = min(CHUNK, PAIRS_PER_BATCH - pB);

  const float4* __restrict__ rowsA =
      reinterpret_cast<const float4*>(emb + (size_t)bA * S_ * D_);
  const float4* __restrict__ rowsB =
      reinterpret_cast<const float4*>(emb + (size_t)bB * S_ * D_);
  const int* __restrict__ lbA = lab + bA * S_;
  const int* __restrict__ lbB = lab + bB * S_;

  // Both label reads in flight together
  int lvA = 0, lvB = 0;
  if (lane <= nA) lvA = lbA[pA + lane];
  if (lane <= nB) lvB = lbB[pB + lane];

  const int nlA = __shfl_down(lvA, 1, 64);
  const int nlB = __shfl_down(lvB, 1, 64);
  const unsigned long long mA =
      __ballot((lane < nA) && (lvA != 0) && (lvA == nlA));
  const unsigned long long mB =
      __ballot((lane < nB) && (lvB != 0) && (lvB == nlB));
  if ((mA | mB) == 0ULL) return 0.0f;

  const unsigned long long rA = mA | (mA << 1);
  const unsigned long long rB = mB | (mB << 1);

  // Issue BOTH row-load sets before any compute (cross-chunk MLP).
  float4 ra[CHUNK + 1], rb[CHUNK + 1];
  #pragma unroll
  for (int i = 0; i <= CHUNK; ++i) {
    if ((rA >> i) & 1ULL) ra[i] = rowsA[(size_t)(pA + i) * (D_ / 4) + lane];
  }
  #pragma unroll
  for (int i = 0; i <= CHUNK; ++i) {
    if ((rB >> i) & 1ULL) rb[i] = rowsB[(size_t)(pB + i) * (D_ / 4) + lane];
  }
  __builtin_amdgcn_sched_barrier(0);   // keep loads hoisted above compute

  float ws = 0.0f;
  #pragma unroll
  for (int i = 0; i < CHUNK; ++i) {
    if ((mA >> i) & 1ULL) {
      const float dx = ra[i].x - ra[i + 1].x;
      const float dy = ra[i].y - ra[i + 1].y;
      const float dz = ra[i].z - ra[i + 1].z;
      const float dw = ra[i].w - ra[i + 1].w;
      float s = dx * dx + dy * dy + dz * dz + dw * dw;
      #pragma unroll
      for (int xm = 1; xm < 64; xm <<= 1) s += __shfl_xor(s, xm, 64);
      ws += sqrtf(s);
    }
  }
  #pragma unroll
  for (int i = 0; i < CHUNK; ++i) {
    if ((mB >> i) & 1ULL) {
      const float dx = rb[i].x - rb[i + 1].x;
      const float dy = rb[i].y - rb[i + 1].y;
      const float dz = rb[i].z - rb[i + 1].z;
      const float dw = rb[i].w - rb[i + 1].w;
      float s = dx * dx + dy * dy + dz * dz + dw * dw;
      #pragma unroll
      for (int xm = 1; xm < 64; xm <<= 1) s += __shfl_xor(s, xm, 64);
      ws += sqrtf(s);
    }
  }
  return ws;
}

// Each wave: 4 chunks as two pipelined pairs; 4 wave partials -> block partial.
__device__ __forceinline__ void block_partial(const float* __restrict__ emb,
                                              const int* __restrict__ lab,
                                              float* __restrict__ partial) {
  const int tid = threadIdx.x;
  const int lane = tid & 63;
  const int w = tid >> 6;
  const int wave = blockIdx.x * WAVES_PER_BLOCK + w;   // 0..2047

  float wsum = pair_sum(emb, lab, wave, wave + NWAVES, lane);
  wsum += pair_sum(emb, lab, wave + 2 * NWAVES, wave + 3 * NWAVES, lane);

  __shared__ float lds[WAVES_PER_BLOCK];
  if (lane == 0) lds[w] = wsum;
  __syncthreads();
  if (tid == 0) {
    partial[blockIdx.x] = ((lds[0] + lds[1]) + lds[2]) + lds[3];
  }
}

// Cooperative single-node version: grid.sync then block 0 reduces.
// __launch_bounds__(256,2): VGPR cap 256 -> the two in-flight row sets
// (~136 VGPR) stay in registers; 2 blocks/CU co-residency is ample for
// NBLOCKS=512 on 256 CUs.
__global__ __launch_bounds__(BLOCK, 2) void ccl_coop_kernel(
    const float* __restrict__ emb, const int* __restrict__ lab,
    float* __restrict__ out, float* __restrict__ partial) {
  block_partial(emb, lab, partial);

  cg::this_grid().sync();

  if (blockIdx.x != 0) return;
  const int tid = threadIdx.x;
  const int lane = tid & 63;
  const int w = tid >> 6;
  float s = 0.0f;
  for (int i = tid; i < NBLOCKS; i += BLOCK) s += partial[i];   // 2 each, fixed order
  #pragma unroll
  for (int xm = 1; xm < 64; xm <<= 1) s += __shfl_xor(s, xm, 64);
  __shared__ float lds2[WAVES_PER_BLOCK];
  if (lane == 0) lds2[w] = s;
  __syncthreads();
  if (tid == 0) {
    out[0] = (((lds2[0] + lds2[1]) + lds2[2]) + lds2[3]) /
             (float)((long long)B_ * S_);
  }
}

// Fallback two-kernel version (proven structure).
__global__ __launch_bounds__(BLOCK, 2) void ccl_body_kernel(
    const float* __restrict__ emb, const int* __restrict__ lab,
    float* __restrict__ partial) {
  block_partial(emb, lab, partial);
}

__global__ __launch_bounds__(BLOCK) void ccl_reduce_kernel(
    const float* __restrict__ partial, float* __restrict__ out) {
  const int tid = threadIdx.x;
  const int lane = tid & 63;
  const int w = tid >> 6;
  float s = 0.0f;
  for (int i = tid; i < NBLOCKS; i += BLOCK) s += partial[i];
  #pragma unroll
  for (int xm = 1; xm < 64; xm <<= 1) s += __shfl_xor(s, xm, 64);
  __shared__ float lds2[WAVES_PER_BLOCK];
  if (lane == 0) lds2[w] = s;
  __syncthreads();
  if (tid == 0) {
    out[0] = (((lds2[0] + lds2[1]) + lds2[2]) + lds2[3]) /
             (float)((long long)B_ * S_);
  }
}

extern "C" void kernel_launch(void* const* d_in, const int* in_sizes, int n_in,
                              void* d_out, int out_size, void* d_ws, size_t ws_size,
                              hipStream_t stream) {
  const float* emb = (const float*)d_in[0];
  const int* lab = (const int*)d_in[1];
  float* out = (float*)d_out;
  float* partial = (float*)d_ws;   // NBLOCKS floats = 2 KiB

  // Host-side, capture-safe, deterministic gating: only take the cooperative
  // path if the runtime confirms full co-residency for this grid.
  int dev = 0;
  (void)hipGetDevice(&dev);
  int coop = 0;
  (void)hipDeviceGetAttribute(&coop, hipDeviceAttributeCooperativeLaunch, dev);
  int ncu = 0;
  (void)hipDeviceGetAttribute(&ncu, hipDeviceAttributeMultiprocessorCount, dev);
  int maxb = 0;
  (void)hipOccupancyMaxActiveBlocksPerMultiprocessor(
      &maxb, (const void*)ccl_coop_kernel, BLOCK, 0);

  if (coop && (long long)maxb * ncu >= NBLOCKS) {
    void* args[4] = {(void*)&emb, (void*)&lab, (void*)&out, (void*)&partial};
    hipError_t e = hipLaunchCooperativeKernel((const void*)ccl_coop_kernel,
                                              dim3(NBLOCKS), dim3(BLOCK), args,
                                              0, stream);
    if (e == hipSuccess) return;
    // else fall through to the two-kernel path
  }

  ccl_body_kernel<<<NBLOCKS, BLOCK, 0, stream>>>(emb, lab, partial);
  ccl_reduce_kernel<<<1, BLOCK, 0, stream>>>(partial, out);
}